// Round 3
// baseline (383.635 us; speedup 1.0000x reference)
//
#include <hip/hip_runtime.h>

#define N_NODES 100000
#define N_EDGES 600000
#define DIM 128
#define NUM_RELS 8
#define NBINS (NUM_RELS * N_NODES)          // 800000 (rel-major: key = r*N + dst)
#define SCAN_NB ((NBINS + 1023) / 1024)     // 782 scan blocks

typedef unsigned int u32;
typedef __attribute__((ext_vector_type(8))) short bf16x8;
typedef __attribute__((ext_vector_type(4))) float f32x4;

// round-nearest-even f32 -> bf16 pair packed in u32
__device__ __forceinline__ u32 pack2_bf16_rn(float lo, float hi) {
    u32 a = __float_as_uint(lo);
    u32 b = __float_as_uint(hi);
    a += 0x7fffu + ((a >> 16) & 1u);
    b += 0x7fffu + ((b >> 16) & 1u);
    return (a >> 16) | (b & 0xffff0000u);
}

// ---------------------------------------------------------------------------
__global__ __launch_bounds__(256) void convert_x(const float* __restrict__ x,
                                                 uint4* __restrict__ x_bf) {
    int t = blockIdx.x * 256 + threadIdx.x;
    if (t >= N_NODES * DIM / 8) return;
    const float4* p = reinterpret_cast<const float4*>(x) + (size_t)t * 2;
    float4 v0 = p[0], v1 = p[1];
    uint4 o;
    o.x = pack2_bf16_rn(v0.x, v0.y);
    o.y = pack2_bf16_rn(v0.z, v0.w);
    o.z = pack2_bf16_rn(v1.x, v1.y);
    o.w = pack2_bf16_rn(v1.z, v1.w);
    x_bf[t] = o;
}

// W chunks -> Wt[c][col][k] bf16 (c=0: W_root, c=1..8: W[c-1]); B-frags read directly.
__global__ __launch_bounds__(256) void transpose_w(const float* __restrict__ W,
                                                   const float* __restrict__ W_root,
                                                   unsigned short* __restrict__ Wt) {
    int t = blockIdx.x * 256 + threadIdx.x;
    if (t >= 9 * DIM * DIM) return;
    int c  = t >> 14;
    int kn = t & 16383;
    int k = kn >> 7, n = kn & 127;
    float v = (c == 0) ? W_root[kn] : W[(size_t)(c - 1) * DIM * DIM + kn];
    u32 b = __float_as_uint(v);
    b += 0x7fffu + ((b >> 16) & 1u);
    Wt[(size_t)c * 16384 + n * 128 + k] = (unsigned short)(b >> 16);
}

// ---------------------------------------------------------------------------
// counting-sort pipeline: hist -> scan(3) -> reorder
__global__ __launch_bounds__(256) void hist_kernel(const int* __restrict__ ei,
                                                   const int* __restrict__ et,
                                                   u32* __restrict__ hist) {
    int e = blockIdx.x * 256 + threadIdx.x;
    if (e >= N_EDGES) return;
    int dst = ei[N_EDGES + e];
    int r   = et[e];
    atomicAdd(&hist[(size_t)r * N_NODES + dst], 1u);
}

__global__ __launch_bounds__(256) void scan1(const u32* __restrict__ hist,
                                             u32* __restrict__ bsum) {
    __shared__ u32 sh[256];
    int t = threadIdx.x;
    size_t base = (size_t)blockIdx.x * 1024 + t * 4;
    u32 s = 0;
#pragma unroll
    for (int j = 0; j < 4; ++j) { size_t i = base + j; if (i < NBINS) s += hist[i]; }
    sh[t] = s; __syncthreads();
    for (int off = 128; off > 0; off >>= 1) {
        if (t < off) sh[t] += sh[t + off];
        __syncthreads();
    }
    if (t == 0) bsum[blockIdx.x] = sh[0];
}

__global__ __launch_bounds__(256) void scan2(u32* __restrict__ bsum, int nb) {
    __shared__ u32 sh[256];
    int t = threadIdx.x;
    u32 v[4]; u32 s = 0;
#pragma unroll
    for (int j = 0; j < 4; ++j) { int i = t * 4 + j; v[j] = (i < nb) ? bsum[i] : 0; s += v[j]; }
    sh[t] = s; __syncthreads();
    for (int off = 1; off < 256; off <<= 1) {
        u32 add = (t >= off) ? sh[t - off] : 0;
        __syncthreads();
        sh[t] += add;
        __syncthreads();
    }
    u32 run = (t > 0) ? sh[t - 1] : 0;
#pragma unroll
    for (int j = 0; j < 4; ++j) { int i = t * 4 + j; if (i < nb) bsum[i] = run; run += v[j]; }
}

__global__ __launch_bounds__(256) void scan3(const u32* __restrict__ hist,
                                             const u32* __restrict__ bsum,
                                             u32* __restrict__ starts,
                                             u32* __restrict__ cursor) {
    __shared__ u32 sh[256];
    int t = threadIdx.x;
    size_t base = (size_t)blockIdx.x * 1024 + t * 4;
    u32 v[4]; u32 s = 0;
#pragma unroll
    for (int j = 0; j < 4; ++j) { size_t i = base + j; v[j] = (i < NBINS) ? hist[i] : 0; s += v[j]; }
    sh[t] = s; __syncthreads();
    for (int off = 1; off < 256; off <<= 1) {
        u32 add = (t >= off) ? sh[t - off] : 0;
        __syncthreads();
        sh[t] += add;
        __syncthreads();
    }
    u32 run = bsum[blockIdx.x] + ((t > 0) ? sh[t - 1] : 0);
#pragma unroll
    for (int j = 0; j < 4; ++j) {
        size_t i = base + j;
        if (i < NBINS) {
            starts[i] = run; cursor[i] = run;
            if (i == NBINS - 1) starts[NBINS] = run + v[j];
            run += v[j];
        }
    }
}

__global__ __launch_bounds__(256) void reorder(const int* __restrict__ ei,
                                               const int* __restrict__ et,
                                               u32* __restrict__ cursor,
                                               u32* __restrict__ ssrc) {
    int e = blockIdx.x * 256 + threadIdx.x;
    if (e >= N_EDGES) return;
    int dst = ei[N_EDGES + e];
    int r   = et[e];
    u32 pos = atomicAdd(&cursor[(size_t)r * N_NODES + dst], 1u);
    ssrc[pos] = (u32)ei[e];
}

// ---------------------------------------------------------------------------
// Fused aggregate + 9-chunk MFMA GEMM. Block = 64 rows, 4 independent waves
// (16 rows each, no __syncthreads). Per relation chunk: batch-load the wave's
// contiguous edge range, stream x-row gathers 8-deep, accumulate means in f32,
// pack to a 4KB XOR-swizzled LDS A-tile, MFMA vs L2-resident B-frags.
#define FLUSH() do { \
    u32 cnt_ = rend - rstart; \
    float sc_ = __builtin_amdgcn_rcpf((float)(cnt_ > 0 ? cnt_ : 1u)); \
    AT[cur * 64 + (((lane >> 2) ^ (cur & 7)) << 2) + (lane & 3)] = pack2_bf16_rn(a0 * sc_, a1 * sc_); \
    a0 = 0.f; a1 = 0.f; \
    rstart = rend; ++cur; \
    rend = __shfl(sv, cur < 16 ? cur + 1 : 16) - S0; \
} while (0)

#define MFMA_CHUNK(C, AF) do { \
    const uint4* Wc_ = Wt + (size_t)(C) * 2048; \
    _Pragma("unroll") \
    for (int ks_ = 0; ks_ < 4; ++ks_) { \
        _Pragma("unroll") \
        for (int ni_ = 0; ni_ < 8; ++ni_) { \
            union { uint4 u; bf16x8 h; } bb_; \
            bb_.u = Wc_[(ni_ * 16 + m) * 16 + ks_ * 4 + g]; \
            accv[ni_] = __builtin_amdgcn_mfma_f32_16x16x32_bf16((AF)[ks_], bb_.h, accv[ni_], 0, 0, 0); \
        } \
    } \
} while (0)

__global__ __launch_bounds__(256) void rgcn_fused(
    const u32*  __restrict__ x32,     // x_bf as u32 rows of 64
    const uint4* __restrict__ x16,    // x_bf as uint4 rows of 16
    const uint4* __restrict__ Wt,     // 9 * 2048
    const u32*  __restrict__ starts,  // [NBINS+1]
    const u32*  __restrict__ ssrc,    // [E] sorted srcs
    const float* __restrict__ bias,
    float* __restrict__ out) {
    __shared__ u32 AT4[4][16 * 64];   // 16 KB, per-wave 4KB slices
    const int tid = threadIdx.x, w = tid >> 6, lane = tid & 63;
    const int g = lane >> 4, m = lane & 15;
    const int rowbase = blockIdx.x * 64 + w * 16;
    if (rowbase >= N_NODES) return;
    u32* AT = AT4[w];

    f32x4 accv[8];
#pragma unroll
    for (int ni = 0; ni < 8; ++ni) accv[ni] = (f32x4)0.0f;

    // ---- chunk 0: root transform, A-frags straight from global
    {
        int row = min(rowbase + m, N_NODES - 1);
        bf16x8 af[4];
        union { uint4 u; bf16x8 h; } cv;
#pragma unroll
        for (int ks = 0; ks < 4; ++ks) { cv.u = x16[(size_t)row * 16 + ks * 4 + g]; af[ks] = cv.h; }
        MFMA_CHUNK(0, af);
    }

    // ---- chunks 1..8: aggregate rel r then MFMA
#pragma unroll 1
    for (int r = 0; r < 8; ++r) {
        u32 sv = 0;
        if (lane < 17) {
            int idx = rowbase + lane;
            sv = starts[(size_t)r * N_NODES + (idx > N_NODES ? N_NODES : idx)];
        }
        const u32 S0 = (u32)__shfl(sv, 0);
        const int total = (int)((u32)__shfl(sv, 16) - S0);

        float a0 = 0.f, a1 = 0.f;
        int cur = 0;
        u32 rstart = 0;
        u32 rend = (u32)__shfl(sv, 1) - S0;

        for (int b64 = 0; b64 < total; b64 += 64) {
            int bn = min(64, total - b64);
            u32 srcs = 0;
            if (lane < bn) srcs = ssrc[S0 + b64 + lane];
            for (int eb = 0; eb < bn; eb += 8) {
                u32 v[8];
#pragma unroll
                for (int j = 0; j < 8; ++j) {
                    u32 s = (u32)__shfl(srcs, eb + j);   // 0 for invalid lanes -> safe addr
                    v[j] = x32[(size_t)s * 64 + lane];
                }
#pragma unroll
                for (int j = 0; j < 8; ++j) {
                    if (eb + j >= bn) break;             // uniform
                    u32 e = (u32)(b64 + eb + j);
                    while (e == rend) { FLUSH(); }       // uniform row-boundary flush
                    a0 += __uint_as_float(v[j] << 16);
                    a1 += __uint_as_float(v[j] & 0xffff0000u);
                }
            }
        }
        while (cur < 16) { FLUSH(); }                    // tail (incl. empty rows)

        const uint4* ATq = reinterpret_cast<const uint4*>(AT);
        bf16x8 af[4];
        union { uint4 u; bf16x8 h; } cv;
#pragma unroll
        for (int ks = 0; ks < 4; ++ks) {
            cv.u = ATq[m * 16 + ((ks * 4 + g) ^ (m & 7))];
            af[ks] = cv.h;
        }
        MFMA_CHUNK(r + 1, af);
    }

    // ---- epilogue: +bias, store f32. C/D: col=m, row=g*4+j
#pragma unroll
    for (int ni = 0; ni < 8; ++ni) {
        float bv = bias[ni * 16 + m];
#pragma unroll
        for (int j = 0; j < 4; ++j) {
            int rr = rowbase + g * 4 + j;
            if (rr < N_NODES) out[(size_t)rr * DIM + ni * 16 + m] = accv[ni][j] + bv;
        }
    }
}

// ---------------------------------------------------------------------------
extern "C" void kernel_launch(void* const* d_in, const int* in_sizes, int n_in,
                              void* d_out, int out_size, void* d_ws, size_t ws_size,
                              hipStream_t stream) {
    const float* x      = (const float*)d_in[0];
    const float* W      = (const float*)d_in[1];
    const float* W_root = (const float*)d_in[2];
    const float* bias   = (const float*)d_in[3];
    const int*   ei     = (const int*)d_in[4];   // [2][E]
    const int*   et     = (const int*)d_in[5];   // [E]
    float* out = (float*)d_out;

    char* ws = (char*)d_ws;
    uint4*          x_bf   = (uint4*)(ws);                        // 25,600,000
    unsigned short* Wt     = (unsigned short*)(ws + 25600000);    //    294,912
    u32*            starts = (u32*)(ws + 25894912);               //  3,200,016 (NBINS+1, padded)
    u32*            cur    = (u32*)(ws + 29094928);               //  3,200,000
    u32*            bsum   = (u32*)(ws + 32294928);               //      4,096
    u32*            ssrc   = (u32*)(ws + 32299024);               //  2,400,000

    convert_x<<<(N_NODES * DIM / 8 + 255) / 256, 256, 0, stream>>>(x, x_bf);
    transpose_w<<<(9 * DIM * DIM + 255) / 256, 256, 0, stream>>>(W, W_root, Wt);
    hipMemsetAsync(cur, 0, (size_t)NBINS * 4, stream);
    hist_kernel<<<(N_EDGES + 255) / 256, 256, 0, stream>>>(ei, et, cur);
    scan1<<<SCAN_NB, 256, 0, stream>>>(cur, bsum);
    scan2<<<1, 256, 0, stream>>>(bsum, SCAN_NB);
    scan3<<<SCAN_NB, 256, 0, stream>>>(cur, bsum, starts, cur /*cursor reuses hist*/);
    reorder<<<(N_EDGES + 255) / 256, 256, 0, stream>>>(ei, et, cur, ssrc);
    rgcn_fused<<<(N_NODES + 63) / 64, 256, 0, stream>>>((const u32*)x_bf, x_bf, (const uint4*)Wt,
                                                        starts, ssrc, bias, out);
}

// Round 4
// 355.107 us; speedup vs baseline: 1.0803x; 1.0803x over previous
//
#include <hip/hip_runtime.h>

#define N_NODES 100000
#define N_EDGES 600000
#define DIM 128
#define NUM_RELS 8
#define NBINS (NUM_RELS * N_NODES)          // 800000, node-major: key = dst*8 + r
#define SCAN_NB ((NBINS + 1023) / 1024)     // 782
#define XBLOCKS 6250                        // convert: 1.6M uint4 / 256
#define TBLOCKS 576                         // 9*16384 / 256
#define HBLOCKS ((N_EDGES + 255) / 256)     // 2344

typedef unsigned int u32;
typedef __attribute__((ext_vector_type(8))) short bf16x8;
typedef __attribute__((ext_vector_type(4))) float f32x4;

__device__ __forceinline__ u32 pack2_bf16_rn(float lo, float hi) {
    u32 a = __float_as_uint(lo);
    u32 b = __float_as_uint(hi);
    a += 0x7fffu + ((a >> 16) & 1u);
    b += 0x7fffu + ((b >> 16) & 1u);
    return (a >> 16) | (b & 0xffff0000u);
}

// ---------------------------------------------------------------------------
// prep = convert_x | transpose_w | hist+rank, partitioned by blockIdx
__global__ __launch_bounds__(256) void prep(
    const float* __restrict__ x, uint4* __restrict__ x_bf,
    const float* __restrict__ W, const float* __restrict__ W_root,
    unsigned short* __restrict__ Wt,
    const int* __restrict__ ei, const int* __restrict__ et,
    u32* __restrict__ hist, u32* __restrict__ rank) {
    int b = blockIdx.x, tid = threadIdx.x;
    if (b < XBLOCKS) {
        int t = b * 256 + tid;                       // < 1,600,000 exact
        const float4* p = reinterpret_cast<const float4*>(x) + (size_t)t * 2;
        float4 v0 = p[0], v1 = p[1];
        uint4 o;
        o.x = pack2_bf16_rn(v0.x, v0.y);
        o.y = pack2_bf16_rn(v0.z, v0.w);
        o.z = pack2_bf16_rn(v1.x, v1.y);
        o.w = pack2_bf16_rn(v1.z, v1.w);
        x_bf[t] = o;
    } else if (b < XBLOCKS + TBLOCKS) {
        int t = (b - XBLOCKS) * 256 + tid;           // < 147,456 exact
        int c  = t >> 14;
        int kn = t & 16383;
        int k = kn >> 7, n = kn & 127;
        float v = (c == 0) ? W_root[kn] : W[(size_t)(c - 1) * DIM * DIM + kn];
        u32 bb = __float_as_uint(v);
        bb += 0x7fffu + ((bb >> 16) & 1u);
        Wt[(size_t)c * 16384 + n * 128 + k] = (unsigned short)(bb >> 16);
    } else {
        int e = (b - XBLOCKS - TBLOCKS) * 256 + tid;
        if (e < N_EDGES) {
            int dst = ei[N_EDGES + e];
            int r   = et[e];
            rank[e] = atomicAdd(&hist[(size_t)dst * NUM_RELS + r], 1u);
        }
    }
}

// ---------------------------------------------------------------------------
__global__ __launch_bounds__(256) void scan1(const u32* __restrict__ hist,
                                             u32* __restrict__ bsum) {
    __shared__ u32 sh[256];
    int t = threadIdx.x;
    size_t base = (size_t)blockIdx.x * 1024 + t * 4;
    u32 s = 0;
#pragma unroll
    for (int j = 0; j < 4; ++j) { size_t i = base + j; if (i < NBINS) s += hist[i]; }
    sh[t] = s; __syncthreads();
    for (int off = 128; off > 0; off >>= 1) {
        if (t < off) sh[t] += sh[t + off];
        __syncthreads();
    }
    if (t == 0) bsum[blockIdx.x] = sh[0];
}

__global__ __launch_bounds__(256) void scan2(u32* __restrict__ bsum, int nb) {
    __shared__ u32 sh[256];
    int t = threadIdx.x;
    u32 v[4]; u32 s = 0;
#pragma unroll
    for (int j = 0; j < 4; ++j) { int i = t * 4 + j; v[j] = (i < nb) ? bsum[i] : 0; s += v[j]; }
    sh[t] = s; __syncthreads();
    for (int off = 1; off < 256; off <<= 1) {
        u32 add = (t >= off) ? sh[t - off] : 0;
        __syncthreads();
        sh[t] += add;
        __syncthreads();
    }
    u32 run = (t > 0) ? sh[t - 1] : 0;
#pragma unroll
    for (int j = 0; j < 4; ++j) { int i = t * 4 + j; if (i < nb) bsum[i] = run; run += v[j]; }
}

__global__ __launch_bounds__(256) void scan3(const u32* __restrict__ hist,
                                             const u32* __restrict__ bsum,
                                             u32* __restrict__ starts) {
    __shared__ u32 sh[256];
    int t = threadIdx.x;
    size_t base = (size_t)blockIdx.x * 1024 + t * 4;
    u32 v[4]; u32 s = 0;
#pragma unroll
    for (int j = 0; j < 4; ++j) { size_t i = base + j; v[j] = (i < NBINS) ? hist[i] : 0; s += v[j]; }
    sh[t] = s; __syncthreads();
    for (int off = 1; off < 256; off <<= 1) {
        u32 add = (t >= off) ? sh[t - off] : 0;
        __syncthreads();
        sh[t] += add;
        __syncthreads();
    }
    u32 run = bsum[blockIdx.x] + ((t > 0) ? sh[t - 1] : 0);
#pragma unroll
    for (int j = 0; j < 4; ++j) {
        size_t i = base + j;
        if (i < NBINS) {
            starts[i] = run;
            if (i == NBINS - 1) starts[NBINS] = run + v[j];
            run += v[j];
        }
    }
}

// no atomics: pos = starts[key] + rank[e]
__global__ __launch_bounds__(256) void reorder(const int* __restrict__ ei,
                                               const int* __restrict__ et,
                                               const u32* __restrict__ starts,
                                               const u32* __restrict__ rank,
                                               u32* __restrict__ ssrc) {
    int e = blockIdx.x * 256 + threadIdx.x;
    if (e >= N_EDGES) return;
    int dst = ei[N_EDGES + e];
    int r   = et[e];
    ssrc[starts[(size_t)dst * NUM_RELS + r] + rank[e]] = (u32)ei[e];
}

// ---------------------------------------------------------------------------
#define MFMA_CHUNK(C, AF) do { \
    const uint4* Wc_ = Wt + (size_t)(C) * 2048; \
    _Pragma("unroll") \
    for (int ks_ = 0; ks_ < 4; ++ks_) { \
        _Pragma("unroll") \
        for (int ni_ = 0; ni_ < 8; ++ni_) { \
            union { uint4 u; bf16x8 h; } bb_; \
            bb_.u = Wc_[(ni_ * 16 + m) * 16 + ks_ * 4 + g]; \
            accv[ni_] = __builtin_amdgcn_mfma_f32_16x16x32_bf16((AF)[ks_], bb_.h, accv[ni_], 0, 0, 0); \
        } \
    } \
} while (0)

#define LOAD_EDGE(EIDX, Q) do { \
    int idx_ = e0 + (EIDX); \
    u32 s_ = (idx_ < 256) ? SRCW[idx_] : ssrc[W0 + idx_]; \
    const uint4* xp_ = x16 + (size_t)s_ * 16 + si * 4; \
    Q[0] = xp_[0]; Q[1] = xp_[1]; Q[2] = xp_[2]; Q[3] = xp_[3]; \
} while (0)

#define ACC_EDGE(Q) do { \
    _Pragma("unroll") \
    for (int q_ = 0; q_ < 4; ++q_) { \
        u32 c0_ = Q[q_].x, c1_ = Q[q_].y, c2_ = Q[q_].z, c3_ = Q[q_].w; \
        a[q_ * 8 + 0] += __uint_as_float(c0_ << 16); \
        a[q_ * 8 + 1] += __uint_as_float(c0_ & 0xffff0000u); \
        a[q_ * 8 + 2] += __uint_as_float(c1_ << 16); \
        a[q_ * 8 + 3] += __uint_as_float(c1_ & 0xffff0000u); \
        a[q_ * 8 + 4] += __uint_as_float(c2_ << 16); \
        a[q_ * 8 + 5] += __uint_as_float(c2_ & 0xffff0000u); \
        a[q_ * 8 + 6] += __uint_as_float(c3_ << 16); \
        a[q_ * 8 + 7] += __uint_as_float(c3_ & 0xffff0000u); \
    } \
} while (0)

// Fused aggregate + 9-chunk MFMA GEMM. 4 independent waves x 16 rows, no
// __syncthreads. Node-major sort => wave's whole edge range contiguous;
// 4-lane group per row aggregates 8 rels with zero shuffles.
__global__ __launch_bounds__(256) void rgcn_fused(
    const uint4* __restrict__ x16,    // x_bf rows of 16 uint4
    const uint4* __restrict__ Wt,     // 9 * 2048 uint4
    const u32*  __restrict__ starts,  // [NBINS+1]
    const u32*  __restrict__ ssrc,    // [E] sorted by dst*8+r
    const float* __restrict__ bias,
    float* __restrict__ out) {
    __shared__ u32 AT4[4][16 * 64];   // 16 KB A-tiles (4 KB per wave)
    __shared__ u32 SRC4[4][256];      // 4 KB src staging (1 KB per wave)
    const int tid = threadIdx.x, w = tid >> 6, lane = tid & 63;
    const int g = lane >> 4, m = lane & 15;       // MFMA roles
    const int gi = lane >> 2, si = lane & 3;      // aggregation roles
    const int rowbase = blockIdx.x * 64 + w * 16;
    if (rowbase >= N_NODES) return;
    u32* AT   = AT4[w];
    u32* SRCW = SRC4[w];
    uint4* ATq = reinterpret_cast<uint4*>(AT);

    f32x4 accv[8];
#pragma unroll
    for (int ni = 0; ni < 8; ++ni) accv[ni] = (f32x4)0.0f;

    const size_t row8 = (size_t)(rowbase + gi) * 8;
    u32 b0   = starts[row8];
    u32 wend = starts[row8 + 8];
    const u32 W0 = (u32)__shfl((int)b0, 0);        // gi=0 lane
    const int wtot = (int)((u32)__shfl((int)wend, 60) - W0);   // gi=15 lane

    // stage the wave's whole edge range (avg ~96, cap 256 w/ global fallback)
#pragma unroll
    for (int k2 = 0; k2 < 4; ++k2) {
        int idx = k2 * 64 + lane;
        u32 v = 0;
        if (idx < wtot) v = ssrc[W0 + idx];
        SRCW[idx] = v;
    }

    // chunk 0: root transform, A-frags straight from global
    {
        int rrow = rowbase + m;
        bf16x8 af[4];
        union { uint4 u; bf16x8 h; } cv;
#pragma unroll
        for (int ks = 0; ks < 4; ++ks) { cv.u = x16[(size_t)rrow * 16 + ks * 4 + g]; af[ks] = cv.h; }
        MFMA_CHUNK(0, af);
    }

    u32 bcur = b0;
#pragma unroll 1
    for (int r = 0; r < 8; ++r) {
        u32 bnext = starts[row8 + r + 1];
        const int cnt = (int)(bnext - bcur);
        const int e0  = (int)(bcur - W0);
        bcur = bnext;

        float a[32];
#pragma unroll
        for (int i = 0; i < 32; ++i) a[i] = 0.0f;

        int e = 0;
        while (e + 2 <= cnt) {
            uint4 qa[4], qb[4];
            LOAD_EDGE(e, qa);
            LOAD_EDGE(e + 1, qb);
            ACC_EDGE(qa);
            ACC_EDGE(qb);
            e += 2;
        }
        if (e < cnt) {
            uint4 qa[4];
            LOAD_EDGE(e, qa);
            ACC_EDGE(qa);
        }

        const float sc = __builtin_amdgcn_rcpf((float)(cnt > 0 ? cnt : 1));
        // rotation-swizzled A-tile write: logical uint4 slot (si*4+tq) -> +gi mod 16
#pragma unroll
        for (int tq = 0; tq < 4; ++tq) {
            uint4 pv;
            pv.x = pack2_bf16_rn(a[tq * 8 + 0] * sc, a[tq * 8 + 1] * sc);
            pv.y = pack2_bf16_rn(a[tq * 8 + 2] * sc, a[tq * 8 + 3] * sc);
            pv.z = pack2_bf16_rn(a[tq * 8 + 4] * sc, a[tq * 8 + 5] * sc);
            pv.w = pack2_bf16_rn(a[tq * 8 + 6] * sc, a[tq * 8 + 7] * sc);
            ATq[gi * 16 + ((si * 4 + tq + gi) & 15)] = pv;
        }

        // A-frag read (same rotation keyed by row m) + MFMA
        bf16x8 af[4];
#pragma unroll
        for (int ks = 0; ks < 4; ++ks) {
            union { uint4 u; bf16x8 h; } cv;
            cv.u = ATq[m * 16 + ((ks * 4 + g + m) & 15)];
            af[ks] = cv.h;
        }
        MFMA_CHUNK(r + 1, af);
    }

    // epilogue: +bias, store f32. C/D: col=m, row=g*4+j
#pragma unroll
    for (int ni = 0; ni < 8; ++ni) {
        float bv = bias[ni * 16 + m];
#pragma unroll
        for (int j = 0; j < 4; ++j) {
            int rr = rowbase + g * 4 + j;
            if (rr < N_NODES) out[(size_t)rr * DIM + ni * 16 + m] = accv[ni][j] + bv;
        }
    }
}

// ---------------------------------------------------------------------------
extern "C" void kernel_launch(void* const* d_in, const int* in_sizes, int n_in,
                              void* d_out, int out_size, void* d_ws, size_t ws_size,
                              hipStream_t stream) {
    const float* x      = (const float*)d_in[0];
    const float* W      = (const float*)d_in[1];
    const float* W_root = (const float*)d_in[2];
    const float* bias   = (const float*)d_in[3];
    const int*   ei     = (const int*)d_in[4];   // [2][E]
    const int*   et     = (const int*)d_in[5];   // [E]
    float* out = (float*)d_out;

    char* ws = (char*)d_ws;
    uint4*          x_bf   = (uint4*)(ws);                        // 25,600,000
    unsigned short* Wt     = (unsigned short*)(ws + 25600000);    //    294,912
    u32*            starts = (u32*)(ws + 25894912);               //  3,200,016
    u32*            hist   = (u32*)(ws + 29094928);               //  3,200,000
    u32*            bsum   = (u32*)(ws + 32294928);               //      4,096
    u32*            rank   = (u32*)(ws + 32299024);               //  2,400,000
    u32*            ssrc   = (u32*)(ws + 34699024);               //  2,400,000
    // total 37,099,024 B

    hipMemsetAsync(hist, 0, (size_t)NBINS * 4, stream);
    prep<<<XBLOCKS + TBLOCKS + HBLOCKS, 256, 0, stream>>>(x, x_bf, W, W_root, Wt, ei, et, hist, rank);
    scan1<<<SCAN_NB, 256, 0, stream>>>(hist, bsum);
    scan2<<<1, 256, 0, stream>>>(bsum, SCAN_NB);
    scan3<<<SCAN_NB, 256, 0, stream>>>(hist, bsum, starts);
    reorder<<<HBLOCKS, 256, 0, stream>>>(ei, et, starts, rank, ssrc);
    rgcn_fused<<<(N_NODES + 63) / 64, 256, 0, stream>>>(x_bf, (const uint4*)Wt, starts, ssrc, bias, out);
}